// Round 1
// baseline (275.704 us; speedup 1.0000x reference)
//
#include <hip/hip_runtime.h>
#include <hip/hip_bf16.h>

typedef float f32x4 __attribute__((ext_vector_type(4)));
typedef short s16x8 __attribute__((ext_vector_type(8)));
typedef unsigned short u16;

#define DEVI static __device__ __forceinline__

constexpr int BB   = 2;
constexpr int SEQ  = 2048;
constexpr int FD   = 1024;
constexpr int NH   = 16;
constexpr int DHD  = 64;
constexpr int MROWS = BB * SEQ; // 4096

DEVI u16 f2bf(float x){
  __hip_bfloat16 h = __float2bfloat16(x);
  return __builtin_bit_cast(u16, h);
}
DEVI float bf2f(u16 u){
  return __bfloat162float(__builtin_bit_cast(__hip_bfloat16, u));
}

// D(f32x4) += A(8 bf16) * B(8 bf16), 16x16x32. Inline asm avoids builtin
// operand-type ambiguity (v8bf16 vs v8i16) across ROCm versions.
DEVI void mfma_bf16(f32x4& acc, s16x8 a, s16x8 b){
  asm("v_mfma_f32_16x16x32_bf16 %0, %1, %2, %0" : "+v"(acc) : "v"(a), "v"(b));
}

// ---------------------------------------------------------------------------
// Weight prep: W[k][n] fp32 -> WT_hi[n][k] bf16 (and optional lo residual).
// ---------------------------------------------------------------------------
__global__ __launch_bounds__(256) void wprep(const float* __restrict__ W,
                                             u16* __restrict__ Th,
                                             u16* __restrict__ Tl)
{
  __shared__ float tile[64][65];
  const int kb = blockIdx.x * 64, nb = blockIdx.y * 64;
  const int t  = threadIdx.x;
  const int r  = t >> 2, c0 = (t & 3) * 16;

  const float* src = W + (size_t)(kb + r) * FD + nb + c0;
  #pragma unroll
  for (int i = 0; i < 16; i += 4){
    float4 v = *reinterpret_cast<const float4*>(src + i);
    tile[r][c0+i+0] = v.x; tile[r][c0+i+1] = v.y;
    tile[r][c0+i+2] = v.z; tile[r][c0+i+3] = v.w;
  }
  __syncthreads();

  s16x8 hA, hB, lA, lB;
  #pragma unroll
  for (int i = 0; i < 8; i++){
    float x0 = tile[c0 + i][r];
    float x1 = tile[c0 + 8 + i][r];
    u16 h0 = f2bf(x0), h1 = f2bf(x1);
    hA[i] = (short)h0; hB[i] = (short)h1;
    lA[i] = (short)f2bf(x0 - bf2f(h0));
    lB[i] = (short)f2bf(x1 - bf2f(h1));
  }
  const size_t o = (size_t)(nb + r) * FD + kb + c0;
  *reinterpret_cast<s16x8*>(Th + o)     = hA;
  *reinterpret_cast<s16x8*>(Th + o + 8) = hB;
  if (Tl){
    *reinterpret_cast<s16x8*>(Tl + o)     = lA;
    *reinterpret_cast<s16x8*>(Tl + o + 8) = lB;
  }
}

// ---------------------------------------------------------------------------
// GEMM: C[M=4096, N=1024] = A[M,K=1024] @ W[K,N] + bias, W given transposed
// (WT[n][k]) in bf16 hi (+lo).  128x128 tile, BK=32, 4 waves, MFMA 16x16x32.
// AMODE 0: A is fp32, converted to bf16-hi during staging (1..2 passes).
// AMODE 1: A is bf16 hi/lo pair (3-pass split GEMM).
// EPI 0: bf16 out, head-split [B,H,N,DH], value=(acc+bias)*oscale
// EPI 1: bf16 out, transposed head-split [B,H,DH,N]
// EPI 2: fp32 out [M,FD]
// ---------------------------------------------------------------------------
template<int AMODE, int EPI, int NPASS>
__global__ __launch_bounds__(256) void gemm_k(
    const void* __restrict__ Ap, const void* __restrict__ Alp,
    const u16* __restrict__ Wh, const u16* __restrict__ Wl,
    const float* __restrict__ bias, void* __restrict__ outp, float oscale)
{
  constexpr int LDT = 40; // 32 cols + 16B pad: keeps ds_*_b128 aligned, spreads banks
  __shared__ u16 sA [128][LDT];
  __shared__ u16 sAl[128][LDT];
  __shared__ u16 sWh[128][LDT];
  __shared__ u16 sWl[128][LDT];

  const int t    = threadIdx.x;
  const int nb0  = blockIdx.x * 128, mb0 = blockIdx.y * 128;
  const int lane = t & 63, w = t >> 6;
  const int r16  = lane & 15, g = lane >> 4;
  const int wm   = (w >> 1) * 64, wn = (w & 1) * 64;

  f32x4 acc[4][4] = {};

  for (int kb = 0; kb < FD; kb += 32){
    __syncthreads();
    #pragma unroll
    for (int s = 0; s < 2; s++){
      const int c = t + 256 * s;
      const int row = c >> 2, col = (c & 3) * 8;
      *reinterpret_cast<s16x8*>(&sWh[row][col]) =
        *reinterpret_cast<const s16x8*>(Wh + (size_t)(nb0 + row) * FD + kb + col);
      if constexpr (NPASS >= 2)
        *reinterpret_cast<s16x8*>(&sWl[row][col]) =
          *reinterpret_cast<const s16x8*>(Wl + (size_t)(nb0 + row) * FD + kb + col);
      if constexpr (AMODE == 0){
        const float* af = reinterpret_cast<const float*>(Ap) + (size_t)(mb0 + row) * FD + kb + col;
        float4 v0 = *reinterpret_cast<const float4*>(af);
        float4 v1 = *reinterpret_cast<const float4*>(af + 4);
        s16x8 hv;
        hv[0]=(short)f2bf(v0.x); hv[1]=(short)f2bf(v0.y);
        hv[2]=(short)f2bf(v0.z); hv[3]=(short)f2bf(v0.w);
        hv[4]=(short)f2bf(v1.x); hv[5]=(short)f2bf(v1.y);
        hv[6]=(short)f2bf(v1.z); hv[7]=(short)f2bf(v1.w);
        *reinterpret_cast<s16x8*>(&sA[row][col]) = hv;
      } else {
        *reinterpret_cast<s16x8*>(&sA[row][col]) =
          *reinterpret_cast<const s16x8*>(reinterpret_cast<const u16*>(Ap)  + (size_t)(mb0 + row) * FD + kb + col);
        *reinterpret_cast<s16x8*>(&sAl[row][col]) =
          *reinterpret_cast<const s16x8*>(reinterpret_cast<const u16*>(Alp) + (size_t)(mb0 + row) * FD + kb + col);
      }
    }
    __syncthreads();

    s16x8 a[4], al[4], bh[4], bl[4];
    #pragma unroll
    for (int i = 0; i < 4; i++){
      a[i]  = *reinterpret_cast<const s16x8*>(&sA [wm + i*16 + r16][g*8]);
      bh[i] = *reinterpret_cast<const s16x8*>(&sWh[wn + i*16 + r16][g*8]);
      if constexpr (NPASS >= 2)
        bl[i] = *reinterpret_cast<const s16x8*>(&sWl[wn + i*16 + r16][g*8]);
      if constexpr (NPASS >= 3)
        al[i] = *reinterpret_cast<const s16x8*>(&sAl[wm + i*16 + r16][g*8]);
    }
    #pragma unroll
    for (int i = 0; i < 4; i++)
      #pragma unroll
      for (int j = 0; j < 4; j++)
        mfma_bf16(acc[i][j], a[i], bh[j]);
    if constexpr (NPASS >= 2){
      #pragma unroll
      for (int i = 0; i < 4; i++)
        #pragma unroll
        for (int j = 0; j < 4; j++)
          mfma_bf16(acc[i][j], a[i], bl[j]);
    }
    if constexpr (NPASS >= 3){
      #pragma unroll
      for (int i = 0; i < 4; i++)
        #pragma unroll
        for (int j = 0; j < 4; j++)
          mfma_bf16(acc[i][j], al[i], bh[j]);
    }
  }

  // epilogue: C row = mb0+wm+i*16+g*4+r ; col = nb0+wn+j*16+r16
  #pragma unroll
  for (int i = 0; i < 4; i++){
    #pragma unroll
    for (int j = 0; j < 4; j++){
      const int ccol = nb0 + wn + j*16 + r16;
      const float bv = bias[ccol];
      #pragma unroll
      for (int r = 0; r < 4; r++){
        const int m = mb0 + wm + i*16 + g*4 + r;
        const float v = (acc[i][j][r] + bv) * oscale;
        if constexpr (EPI == 0){
          const int b = m >> 11, n = m & (SEQ - 1);
          const int h = ccol >> 6, d = ccol & 63;
          reinterpret_cast<u16*>(outp)[(((size_t)(b*NH + h))*SEQ + n)*DHD + d] = f2bf(v);
        } else if constexpr (EPI == 1){
          const int b = m >> 11, n = m & (SEQ - 1);
          const int h = ccol >> 6, d = ccol & 63;
          reinterpret_cast<u16*>(outp)[(((size_t)(b*NH + h))*DHD + d)*SEQ + n] = f2bf(v);
        } else {
          reinterpret_cast<float*>(outp)[(size_t)m * FD + ccol] = v;
        }
      }
    }
  }
}

// ---------------------------------------------------------------------------
// Flash attention: one block = 4 waves, 64 q-rows (16 per wave), per (b,h).
// Q2/K2: [B,H,N,DH] bf16 (Q pre-scaled by 1/8).  Vt2: [B,H,DH,N] bf16.
// Output: AO hi/lo bf16 [M, FD] (heads merged) for the split O-GEMM.
// ---------------------------------------------------------------------------
__global__ __launch_bounds__(256) void attn_k(
    const u16* __restrict__ Q2, const u16* __restrict__ K2, const u16* __restrict__ Vt2,
    u16* __restrict__ AOh, u16* __restrict__ AOl)
{
  __shared__ u16 sK[64][72];
  __shared__ u16 sV[64][72];
  __shared__ u16 sP[4][16][72];

  const int bh = blockIdx.y, qt = blockIdx.x;
  const int t = threadIdx.x, w = t >> 6, lane = t & 63;
  const int r16 = lane & 15, g = lane >> 4;

  const u16* Qb = Q2 + ((size_t)bh * SEQ + qt*64 + w*16) * DHD;
  s16x8 qf[2];
  #pragma unroll
  for (int s = 0; s < 2; s++)
    qf[s] = *reinterpret_cast<const s16x8*>(Qb + r16*DHD + s*32 + g*8);

  f32x4 o[4] = {};
  float mrun[4], lrun[4];
  #pragma unroll
  for (int r = 0; r < 4; r++){ mrun[r] = -1e30f; lrun[r] = 0.f; }

  const u16* Kb = K2  + (size_t)bh * SEQ * DHD;
  const u16* Vb = Vt2 + (size_t)bh * DHD * SEQ;

  for (int kt = 0; kt < SEQ/64; kt++){
    __syncthreads();
    #pragma unroll
    for (int s = 0; s < 2; s++){
      const int c = t + 256*s;
      const int row = c >> 3, col = (c & 7) * 8;
      *reinterpret_cast<s16x8*>(&sK[row][col]) =
        *reinterpret_cast<const s16x8*>(Kb + (size_t)(kt*64 + row)*DHD + col);
      *reinterpret_cast<s16x8*>(&sV[row][col]) =
        *reinterpret_cast<const s16x8*>(Vb + (size_t)row*SEQ + kt*64 + col);
    }
    __syncthreads();

    // S tile: rows = wave's 16 q (lane layout: row g*4+r), cols = 64 kv
    f32x4 sc[4] = {};
    #pragma unroll
    for (int j = 0; j < 4; j++)
      #pragma unroll
      for (int s = 0; s < 2; s++){
        s16x8 kf = *reinterpret_cast<const s16x8*>(&sK[j*16 + r16][s*32 + g*8]);
        mfma_bf16(sc[j], qf[s], kf);
      }

    // online softmax (rows live in 16-lane groups; xor-shuffle <=8 stays in group)
    float mt[4];
    #pragma unroll
    for (int r = 0; r < 4; r++)
      mt[r] = fmaxf(fmaxf(sc[0][r], sc[1][r]), fmaxf(sc[2][r], sc[3][r]));
    #pragma unroll
    for (int off = 1; off <= 8; off <<= 1)
      #pragma unroll
      for (int r = 0; r < 4; r++)
        mt[r] = fmaxf(mt[r], __shfl_xor(mt[r], off, 64));

    float alp[4];
    #pragma unroll
    for (int r = 0; r < 4; r++){
      const float mn = fmaxf(mrun[r], mt[r]);
      alp[r] = __expf(mrun[r] - mn);
      mrun[r] = mn;
    }
    #pragma unroll
    for (int j = 0; j < 4; j++)
      #pragma unroll
      for (int r = 0; r < 4; r++)
        sc[j][r] = __expf(sc[j][r] - mrun[r]);

    float ps[4];
    #pragma unroll
    for (int r = 0; r < 4; r++)
      ps[r] = (sc[0][r] + sc[1][r]) + (sc[2][r] + sc[3][r]);
    #pragma unroll
    for (int off = 1; off <= 8; off <<= 1)
      #pragma unroll
      for (int r = 0; r < 4; r++)
        ps[r] += __shfl_xor(ps[r], off, 64);
    #pragma unroll
    for (int r = 0; r < 4; r++)
      lrun[r] = lrun[r] * alp[r] + ps[r];
    #pragma unroll
    for (int n = 0; n < 4; n++)
      #pragma unroll
      for (int r = 0; r < 4; r++)
        o[n][r] *= alp[r];

    // P: C-layout -> A-layout via per-wave LDS roundtrip
    #pragma unroll
    for (int j = 0; j < 4; j++)
      #pragma unroll
      for (int r = 0; r < 4; r++)
        sP[w][g*4 + r][j*16 + r16] = f2bf(sc[j][r]);

    #pragma unroll
    for (int n = 0; n < 4; n++)
      #pragma unroll
      for (int ks = 0; ks < 2; ks++){
        s16x8 pf = *reinterpret_cast<const s16x8*>(&sP[w][r16][ks*32 + g*8]);
        s16x8 vf = *reinterpret_cast<const s16x8*>(&sV[n*16 + r16][ks*32 + g*8]);
        mfma_bf16(o[n], pf, vf);
      }
  }

  const int b = bh >> 4, h = bh & 15;
  #pragma unroll
  for (int n = 0; n < 4; n++)
    #pragma unroll
    for (int r = 0; r < 4; r++){
      const float v = o[n][r] / lrun[r];
      const int row = qt*64 + w*16 + g*4 + r;
      const size_t off = ((size_t)(b*SEQ + row)) * FD + h*64 + n*16 + r16;
      const u16 hh = f2bf(v);
      AOh[off] = hh;
      AOl[off] = f2bf(v - bf2f(hh));
    }
}

// ---------------------------------------------------------------------------
extern "C" void kernel_launch(void* const* d_in, const int* in_sizes, int n_in,
                              void* d_out, int out_size, void* d_ws, size_t ws_size,
                              hipStream_t stream)
{
  const float* q  = (const float*)d_in[0];
  const float* k  = (const float*)d_in[1];
  const float* v  = (const float*)d_in[2];
  const float* Wq = (const float*)d_in[3];
  const float* bq = (const float*)d_in[4];
  const float* Wk = (const float*)d_in[5];
  const float* bk = (const float*)d_in[6];
  const float* Wv = (const float*)d_in[7];
  const float* bv = (const float*)d_in[8];
  const float* Wo = (const float*)d_in[9];
  const float* bo = (const float*)d_in[10];
  float* out = (float*)d_out;
  (void)in_sizes; (void)n_in; (void)out_size; (void)ws_size;

  char* ws = (char*)d_ws;
  size_t off = 0;
  auto alloc = [&](size_t bytes) -> char* {
    char* p = ws + off;
    off += (bytes + 255) & ~(size_t)255;
    return p;
  };
  const size_t WB = (size_t)FD * FD * sizeof(u16);          // 2 MB
  u16* WqTh = (u16*)alloc(WB);
  u16* WkTh = (u16*)alloc(WB);
  u16* WvTh = (u16*)alloc(WB);
  u16* WoTh = (u16*)alloc(WB);
  u16* WoTl = (u16*)alloc(WB);
  const size_t QB = (size_t)BB * NH * SEQ * DHD * sizeof(u16); // 8 MB
  u16* Q2  = (u16*)alloc(QB);
  u16* K2  = (u16*)alloc(QB);
  u16* Vt2 = (u16*)alloc(QB);
  const size_t AB = (size_t)MROWS * FD * sizeof(u16);          // 8 MB
  u16* AOh = (u16*)alloc(AB);
  u16* AOl = (u16*)alloc(AB);
  // total ws use: ~50 MB

  dim3 blk(256);
  wprep<<<dim3(16,16), blk, 0, stream>>>(Wq, WqTh, nullptr);
  wprep<<<dim3(16,16), blk, 0, stream>>>(Wk, WkTh, nullptr);
  wprep<<<dim3(16,16), blk, 0, stream>>>(Wv, WvTh, nullptr);
  wprep<<<dim3(16,16), blk, 0, stream>>>(Wo, WoTh, WoTl);

  // projections (plain bf16, errors attenuate through attention);
  // SCALE=1/8 (exact pow2) folded into Q after bias, matching reference.
  gemm_k<0,0,1><<<dim3(8,32), blk, 0, stream>>>(q, nullptr, WqTh, nullptr, bq, Q2, 0.125f);
  gemm_k<0,0,1><<<dim3(8,32), blk, 0, stream>>>(k, nullptr, WkTh, nullptr, bk, K2, 1.0f);
  gemm_k<0,1,1><<<dim3(8,32), blk, 0, stream>>>(v, nullptr, WvTh, nullptr, bv, Vt2, 1.0f);

  attn_k<<<dim3(SEQ/64, BB*NH), blk, 0, stream>>>(Q2, K2, Vt2, AOh, AOl);

  // output projection: full 3-pass split-bf16 (errors hit output directly)
  gemm_k<1,2,3><<<dim3(8,32), blk, 0, stream>>>(AOh, AOl, WoTh, WoTl, bo, out, 1.0f);
}

// Round 3
// 195.114 us; speedup vs baseline: 1.4130x; 1.4130x over previous
//
#include <hip/hip_runtime.h>
#include <hip/hip_bf16.h>

typedef float f32x4  __attribute__((ext_vector_type(4)));
typedef float f32x16 __attribute__((ext_vector_type(16)));
typedef short s16x8  __attribute__((ext_vector_type(8)));
typedef unsigned int u32;
typedef unsigned short u16;
typedef u16 u16x4 __attribute__((ext_vector_type(4)));
typedef u32 u32x4 __attribute__((ext_vector_type(4)));

#define DEVI static __device__ __forceinline__

constexpr int BB   = 2;
constexpr int SEQ  = 2048;
constexpr int FD   = 1024;
constexpr int NH   = 16;
constexpr int DHD  = 64;

DEVI u16 f2bf(float x){
  __hip_bfloat16 h = __float2bfloat16(x);
  return __builtin_bit_cast(u16, h);
}
DEVI float bf2f(u16 u){
  return __bfloat162float(__builtin_bit_cast(__hip_bfloat16, u));
}
DEVI u32 pack2(float a, float b){
  return (u32)f2bf(a) | ((u32)f2bf(b) << 16);
}

DEVI void mfma_bf16(f32x4& acc, s16x8 a, s16x8 b){
  asm("v_mfma_f32_16x16x32_bf16 %0, %1, %2, %0" : "+v"(acc) : "v"(a), "v"(b));
}
DEVI void mfma32(f32x16& acc, s16x8 a, s16x8 b){
  asm("v_mfma_f32_32x32x16_bf16 %0, %1, %2, %0" : "+v"(acc) : "v"(a), "v"(b));
}
// v_permlane32_swap_b32 vdst, vsrc:
//   vdst.lanes[32:63] <-> vsrc.lanes[0:31]; vdst.lo and vsrc.hi unchanged.
// (Direction verified against the guide's cvt_pk+permlane recipe: one swap of
//  (kv01-word, kv89-word) must yield frag words w0 and w2 both usable.)
DEVI void plswap(u32& a, u32& b){
  asm("v_permlane32_swap_b32 %0, %1" : "+v"(a), "+v"(b));
}

#define AS1C(p) ((const __attribute__((address_space(1))) void*)(p))
#define AS3(p)  ((__attribute__((address_space(3))) void*)(p))

// ---------------------------------------------------------------------------
// Weight prep: W[k][n] fp32 -> WT_hi[n][k] bf16 (and optional lo residual).
// ---------------------------------------------------------------------------
__global__ __launch_bounds__(256) void wprep(const float* __restrict__ W,
                                             u16* __restrict__ Th,
                                             u16* __restrict__ Tl)
{
  __shared__ float tile[64][65];
  const int kb = blockIdx.x * 64, nb = blockIdx.y * 64;
  const int t  = threadIdx.x;
  const int r  = t >> 2, c0 = (t & 3) * 16;

  const float* src = W + (size_t)(kb + r) * FD + nb + c0;
  #pragma unroll
  for (int i = 0; i < 16; i += 4){
    float4 v = *reinterpret_cast<const float4*>(src + i);
    tile[r][c0+i+0] = v.x; tile[r][c0+i+1] = v.y;
    tile[r][c0+i+2] = v.z; tile[r][c0+i+3] = v.w;
  }
  __syncthreads();

  s16x8 hA, hB, lA, lB;
  #pragma unroll
  for (int i = 0; i < 8; i++){
    float x0 = tile[c0 + i][r];
    float x1 = tile[c0 + 8 + i][r];
    u16 h0 = f2bf(x0), h1 = f2bf(x1);
    hA[i] = (short)h0; hB[i] = (short)h1;
    lA[i] = (short)f2bf(x0 - bf2f(h0));
    lB[i] = (short)f2bf(x1 - bf2f(h1));
  }
  const size_t o = (size_t)(nb + r) * FD + kb + c0;
  *reinterpret_cast<s16x8*>(Th + o)     = hA;
  *reinterpret_cast<s16x8*>(Th + o + 8) = hB;
  if (Tl){
    *reinterpret_cast<s16x8*>(Tl + o)     = lA;
    *reinterpret_cast<s16x8*>(Tl + o + 8) = lB;
  }
}

// ---------------------------------------------------------------------------
// GEMM: C[M=4096, N=1024] = A[M,K=1024] @ W[K,N] + bias, W given transposed
// (WT[n][k]) in bf16 hi (+lo).  128x128 tile, BK=32, 4 waves, MFMA 16x16x32.
// AMODE 0: A fp32, converted to bf16 during staging.  AMODE 1: A bf16 (hi[/lo]).
// EPI 0: bf16 head-split [B,H,N,DH] * oscale; EPI 1: [B,H,DH,N]; EPI 2: fp32 [M,FD].
// NPASS: 1 = Ah*Wh; 2 = +Ah*Wl; 3 = +Al*Wh.
// ---------------------------------------------------------------------------
template<int AMODE, int EPI, int NPASS>
__global__ __launch_bounds__(256) void gemm_k(
    const void* __restrict__ Ap, const void* __restrict__ Alp,
    const u16* __restrict__ Wh, const u16* __restrict__ Wl,
    const float* __restrict__ bias, void* __restrict__ outp, float oscale)
{
  constexpr int LDT = 40;
  __shared__ u16 sA [128][LDT];
  __shared__ u16 sAl[(NPASS>=3)?128:1][LDT];
  __shared__ u16 sWh[128][LDT];
  __shared__ u16 sWl[(NPASS>=2)?128:1][LDT];

  const int t    = threadIdx.x;
  const int nb0  = blockIdx.x * 128, mb0 = blockIdx.y * 128;
  const int lane = t & 63, w = t >> 6;
  const int r16  = lane & 15, g = lane >> 4;
  const int wm   = (w >> 1) * 64, wn = (w & 1) * 64;

  f32x4 acc[4][4] = {};

  for (int kb = 0; kb < FD; kb += 32){
    __syncthreads();
    #pragma unroll
    for (int s = 0; s < 2; s++){
      const int c = t + 256 * s;
      const int row = c >> 2, col = (c & 3) * 8;
      *reinterpret_cast<s16x8*>(&sWh[row][col]) =
        *reinterpret_cast<const s16x8*>(Wh + (size_t)(nb0 + row) * FD + kb + col);
      if constexpr (NPASS >= 2)
        *reinterpret_cast<s16x8*>(&sWl[row][col]) =
          *reinterpret_cast<const s16x8*>(Wl + (size_t)(nb0 + row) * FD + kb + col);
      if constexpr (AMODE == 0){
        const float* af = reinterpret_cast<const float*>(Ap) + (size_t)(mb0 + row) * FD + kb + col;
        float4 v0 = *reinterpret_cast<const float4*>(af);
        float4 v1 = *reinterpret_cast<const float4*>(af + 4);
        s16x8 hv;
        hv[0]=(short)f2bf(v0.x); hv[1]=(short)f2bf(v0.y);
        hv[2]=(short)f2bf(v0.z); hv[3]=(short)f2bf(v0.w);
        hv[4]=(short)f2bf(v1.x); hv[5]=(short)f2bf(v1.y);
        hv[6]=(short)f2bf(v1.z); hv[7]=(short)f2bf(v1.w);
        *reinterpret_cast<s16x8*>(&sA[row][col]) = hv;
      } else {
        *reinterpret_cast<s16x8*>(&sA[row][col]) =
          *reinterpret_cast<const s16x8*>(reinterpret_cast<const u16*>(Ap)  + (size_t)(mb0 + row) * FD + kb + col);
        if constexpr (NPASS >= 3)
          *reinterpret_cast<s16x8*>(&sAl[row][col]) =
            *reinterpret_cast<const s16x8*>(reinterpret_cast<const u16*>(Alp) + (size_t)(mb0 + row) * FD + kb + col);
      }
    }
    __syncthreads();

    s16x8 a[4], al[4], bh[4], bl[4];
    #pragma unroll
    for (int i = 0; i < 4; i++){
      a[i]  = *reinterpret_cast<const s16x8*>(&sA [wm + i*16 + r16][g*8]);
      bh[i] = *reinterpret_cast<const s16x8*>(&sWh[wn + i*16 + r16][g*8]);
      if constexpr (NPASS >= 2)
        bl[i] = *reinterpret_cast<const s16x8*>(&sWl[wn + i*16 + r16][g*8]);
      if constexpr (NPASS >= 3)
        al[i] = *reinterpret_cast<const s16x8*>(&sAl[wm + i*16 + r16][g*8]);
    }
    #pragma unroll
    for (int i = 0; i < 4; i++)
      #pragma unroll
      for (int j = 0; j < 4; j++)
        mfma_bf16(acc[i][j], a[i], bh[j]);
    if constexpr (NPASS >= 2){
      #pragma unroll
      for (int i = 0; i < 4; i++)
        #pragma unroll
        for (int j = 0; j < 4; j++)
          mfma_bf16(acc[i][j], a[i], bl[j]);
    }
    if constexpr (NPASS >= 3){
      #pragma unroll
      for (int i = 0; i < 4; i++)
        #pragma unroll
        for (int j = 0; j < 4; j++)
          mfma_bf16(acc[i][j], al[i], bh[j]);
    }
  }

  #pragma unroll
  for (int i = 0; i < 4; i++){
    #pragma unroll
    for (int j = 0; j < 4; j++){
      const int ccol = nb0 + wn + j*16 + r16;
      const float bv = bias[ccol];
      #pragma unroll
      for (int r = 0; r < 4; r++){
        const int m = mb0 + wm + i*16 + g*4 + r;
        const float v = (acc[i][j][r] + bv) * oscale;
        if constexpr (EPI == 0){
          const int b = m >> 11, n = m & (SEQ - 1);
          const int h = ccol >> 6, d = ccol & 63;
          reinterpret_cast<u16*>(outp)[(((size_t)(b*NH + h))*SEQ + n)*DHD + d] = f2bf(v);
        } else if constexpr (EPI == 1){
          const int b = m >> 11, n = m & (SEQ - 1);
          const int h = ccol >> 6, d = ccol & 63;
          reinterpret_cast<u16*>(outp)[(((size_t)(b*NH + h))*DHD + d)*SEQ + n] = f2bf(v);
        } else {
          reinterpret_cast<float*>(outp)[(size_t)m * FD + ccol] = v;
        }
      }
    }
  }
}

// ---------------------------------------------------------------------------
// Flash attention, swapped-operand 32x32 form.
// Block = 4 waves, 128 q-rows (32/wave), KV tiles of 64, per (b,h).
// Q2/K2: [B,H,N,64] bf16 (Q pre-scaled by 1/8). Vt2: [B,H,64,N] bf16.
// S^T = mfma(K, Q): lane's col q = lane&31; kv row (reg) = (r&3)+8*(r>>2)+4*hi.
// O^T = mfma(V^T, P^T): same col-q layout -> softmax state scalar per lane.
// K/V LDS XOR-swizzled (byte ^= (row&7)<<4), staged by global_load_lds from
// pre-swizzled source addresses, double-buffered (stage kt+1 before compute kt).
// ---------------------------------------------------------------------------
__global__ __launch_bounds__(256) void attn_k(
    const u16* __restrict__ Q2, const u16* __restrict__ K2, const u16* __restrict__ Vt2,
    u16* __restrict__ AOh)
{
  __shared__ u16 sK[2][64*64];
  __shared__ u16 sV[2][64*64];

  const int bh = blockIdx.y, qt = blockIdx.x;
  const int t = threadIdx.x, w = t >> 6, lane = t & 63;
  const int l31 = lane & 31, hi = lane >> 5;

  const u16* Kb = K2  + (size_t)bh * SEQ * DHD;
  const u16* Vb = Vt2 + (size_t)bh * DHD * SEQ;

  // staging: wave w covers rows w*16+i*8 .. +7 (i=0,1); lane -> row w*16+i*8+(lane>>3),
  // 16B chunk (lane&7). Source chunk pre-swizzled: c ^ (row&7).
  const int srow8  = lane >> 3;                 // 0..7 == row&7
  const int schunk = ((lane & 7) ^ srow8) * 8;  // u16 offset of 16B chunk

  // Q fragments: lane holds Q[q = qbase + l31][d = dk*16 + hi*8 + 0..7]
  const int qrow = qt*128 + w*32 + l31;
  const u16* Qrow = Q2 + ((size_t)bh * SEQ + qrow) * DHD;
  s16x8 qf[4];
  #pragma unroll
  for (int dk = 0; dk < 4; dk++)
    qf[dk] = *reinterpret_cast<const s16x8*>(Qrow + dk*16 + hi*8);

  f32x16 ot0 = {}, ot1 = {};
  float mrun = -1e30f, lrun = 0.f;

  auto stage_tile = [&](int buf, int kt){
    #pragma unroll
    for (int i = 0; i < 2; i++){
      const int row = w*16 + i*8 + srow8;
      const u16* kg = Kb + (size_t)(kt*64 + row) * DHD + schunk;
      const u16* vg = Vb + (size_t)row * SEQ + kt*64 + schunk;
      __builtin_amdgcn_global_load_lds(AS1C(kg), AS3(&sK[buf][(w*16 + i*8)*64]), 16, 0, 0);
      __builtin_amdgcn_global_load_lds(AS1C(vg), AS3(&sV[buf][(w*16 + i*8)*64]), 16, 0, 0);
    }
  };
  auto lds16 = [](const u16* base, int row, int colbyte) -> s16x8 {
    int off = (row << 7) + colbyte;
    off ^= (row & 7) << 4;
    return *reinterpret_cast<const s16x8*>(reinterpret_cast<const char*>(base) + off);
  };

  stage_tile(0, 0);
  __syncthreads();

  for (int kt = 0; kt < SEQ/64; kt++){
    const int buf = kt & 1;
    if (kt + 1 < SEQ/64) stage_tile(buf ^ 1, kt + 1);

    // ---- S^T = K · Q^T  (two 32-kv subtiles) ----
    f32x16 st0 = {}, st1 = {};
    #pragma unroll
    for (int dk = 0; dk < 4; dk++){
      s16x8 kf0 = lds16(sK[buf], l31,      dk*32 + hi*16);
      s16x8 kf1 = lds16(sK[buf], 32 + l31, dk*32 + hi*16);
      mfma32(st0, kf0, qf[dk]);
      mfma32(st1, kf1, qf[dk]);
    }

    // ---- online softmax, scalar state per lane (q = lane&31) ----
    float mx[8];
    #pragma unroll
    for (int r = 0; r < 8; r++)
      mx[r] = fmaxf(fmaxf(st0[r], st0[r+8]), fmaxf(st1[r], st1[r+8]));
    float pmax = fmaxf(fmaxf(fmaxf(mx[0],mx[1]), fmaxf(mx[2],mx[3])),
                       fmaxf(fmaxf(mx[4],mx[5]), fmaxf(mx[6],mx[7])));
    pmax = fmaxf(pmax, __shfl_xor(pmax, 32, 64));

    if (!__all(pmax <= mrun + 8.f)){      // defer-max (T13)
      float mnew = fmaxf(mrun, pmax);
      float alp = __expf(mrun - mnew);
      mrun = mnew;
      lrun *= alp;
      #pragma unroll
      for (int r = 0; r < 16; r++){ ot0[r] *= alp; ot1[r] *= alp; }
    }

    #pragma unroll
    for (int r = 0; r < 16; r++){
      st0[r] = __expf(st0[r] - mrun);
      st1[r] = __expf(st1[r] - mrun);
    }
    float s8[8];
    #pragma unroll
    for (int r = 0; r < 8; r++)
      s8[r] = (st0[r] + st0[r+8]) + (st1[r] + st1[r+8]);
    float psum = ((s8[0]+s8[1])+(s8[2]+s8[3])) + ((s8[4]+s8[5])+(s8[6]+s8[7]));
    psum += __shfl_xor(psum, 32, 64);
    lrun += psum;

    // ---- P^T -> B-fragments via pack + permlane32_swap ----
    // pw[2*g2+p] covers kv = 8*g2 + 4*hi + 2p..+1 within its 32-subtile.
    // Frag word j (lane) must cover kv = ks*16 + hi*8 + 2j..+1.
    u32 pw[16];
    #pragma unroll
    for (int g2 = 0; g2 < 4; g2++){
      pw[g2*2+0]   = pack2(st0[g2*4+0], st0[g2*4+1]);
      pw[g2*2+1]   = pack2(st0[g2*4+2], st0[g2*4+3]);
      pw[8+g2*2+0] = pack2(st1[g2*4+0], st1[g2*4+1]);
      pw[8+g2*2+1] = pack2(st1[g2*4+2], st1[g2*4+3]);
    }
    s16x8 pb[4];
    #pragma unroll
    for (int ks = 0; ks < 4; ks++){
      const int e = (ks>>1)*8 + (ks&1)*4;
      u32 w0 = pw[e+0], w1 = pw[e+1], w2 = pw[e+2], w3 = pw[e+3];
      // dst-HIGH <-> src-LOW: after plswap(w0,w2):
      //   w0 = {hi=0: own pw[e],   hi=1: partner pw[e+2]} = frag word0
      //   w2 = {hi=0: partner pw[e], hi=1: own pw[e+2]}   = frag word2
      plswap(w0, w2);
      plswap(w1, w3);
      u32x4 wv = { w0, w1, w2, w3 };
      pb[ks] = __builtin_bit_cast(s16x8, wv);
    }

    // ---- O^T += V^T · P^T ----
    #pragma unroll
    for (int ks = 0; ks < 4; ks++){
      s16x8 vf0 = lds16(sV[buf], l31,      ks*32 + hi*16);
      s16x8 vf1 = lds16(sV[buf], 32 + l31, ks*32 + hi*16);
      mfma32(ot0, vf0, pb[ks]);
      mfma32(ot1, vf1, pb[ks]);
    }

    __syncthreads();   // drains stage loads (vmcnt 0) + guards buffer reuse
  }

  // ---- epilogue: O^T[d][q] -> AO[b*SEQ+q][h*64+d], 8B packed stores ----
  const float inv = 1.0f / lrun;
  const int b = bh >> 4, h = bh & 15;
  u16* orow = AOh + ((size_t)b*SEQ + qrow) * FD + h*64;
  #pragma unroll
  for (int r4 = 0; r4 < 4; r4++){
    const int d0 = r4*8 + hi*4;
    u16x4 v0, v1;
    #pragma unroll
    for (int j = 0; j < 4; j++){
      v0[j] = f2bf(ot0[r4*4+j] * inv);
      v1[j] = f2bf(ot1[r4*4+j] * inv);
    }
    *reinterpret_cast<u16x4*>(orow + d0)      = v0;
    *reinterpret_cast<u16x4*>(orow + 32 + d0) = v1;
  }
}

// ---------------------------------------------------------------------------
extern "C" void kernel_launch(void* const* d_in, const int* in_sizes, int n_in,
                              void* d_out, int out_size, void* d_ws, size_t ws_size,
                              hipStream_t stream)
{
  const float* q  = (const float*)d_in[0];
  const float* k  = (const float*)d_in[1];
  const float* v  = (const float*)d_in[2];
  const float* Wq = (const float*)d_in[3];
  const float* bq = (const float*)d_in[4];
  const float* Wk = (const float*)d_in[5];
  const float* bk = (const float*)d_in[6];
  const float* Wv = (const float*)d_in[7];
  const float* bv = (const float*)d_in[8];
  const float* Wo = (const float*)d_in[9];
  const float* bo = (const float*)d_in[10];
  float* out = (float*)d_out;
  (void)in_sizes; (void)n_in; (void)out_size; (void)ws_size;

  char* ws = (char*)d_ws;
  size_t off = 0;
  auto alloc = [&](size_t bytes) -> char* {
    char* p = ws + off;
    off += (bytes + 255) & ~(size_t)255;
    return p;
  };
  const size_t WB = (size_t)FD * FD * sizeof(u16);             // 2 MB
  u16* WqTh = (u16*)alloc(WB);
  u16* WkTh = (u16*)alloc(WB);
  u16* WvTh = (u16*)alloc(WB);
  u16* WoTh = (u16*)alloc(WB);
  const size_t QB = (size_t)BB * NH * SEQ * DHD * sizeof(u16); // 8 MB
  u16* Q2  = (u16*)alloc(QB);
  u16* K2  = (u16*)alloc(QB);
  u16* Vt2 = (u16*)alloc(QB);
  const size_t AB = (size_t)BB * SEQ * FD * sizeof(u16);       // 8 MB
  u16* AOh = (u16*)alloc(AB);

  dim3 blk(256);
  wprep<<<dim3(16,16), blk, 0, stream>>>(Wq, WqTh, nullptr);
  wprep<<<dim3(16,16), blk, 0, stream>>>(Wk, WkTh, nullptr);
  wprep<<<dim3(16,16), blk, 0, stream>>>(Wv, WvTh, nullptr);
  wprep<<<dim3(16,16), blk, 0, stream>>>(Wo, WoTh, nullptr);

  // projections (plain bf16; SCALE=1/8 exact pow2, folded into Q)
  gemm_k<0,0,1><<<dim3(8,32), blk, 0, stream>>>(q, nullptr, WqTh, nullptr, bq, Q2, 0.125f);
  gemm_k<0,0,1><<<dim3(8,32), blk, 0, stream>>>(k, nullptr, WkTh, nullptr, bk, K2, 1.0f);
  gemm_k<0,1,1><<<dim3(8,32), blk, 0, stream>>>(v, nullptr, WvTh, nullptr, bv, Vt2, 1.0f);

  attn_k<<<dim3(SEQ/128, BB*NH), blk, 0, stream>>>(Q2, K2, Vt2, AOh);

  // output projection: 1-pass bf16 (error budget verified by round-1 measurement)
  gemm_k<1,2,1><<<dim3(8,32), blk, 0, stream>>>(AOh, nullptr, WoTh, nullptr, bo, out, 1.0f);
}

// Round 4
// 153.873 us; speedup vs baseline: 1.7918x; 1.2680x over previous
//
#include <hip/hip_runtime.h>
#include <hip/hip_bf16.h>

typedef float f32x4  __attribute__((ext_vector_type(4)));
typedef float f32x16 __attribute__((ext_vector_type(16)));
typedef short s16x8  __attribute__((ext_vector_type(8)));
typedef unsigned int u32;
typedef unsigned short u16;
typedef u16 u16x4 __attribute__((ext_vector_type(4)));
typedef u32 u32x4 __attribute__((ext_vector_type(4)));

#define DEVI static __device__ __forceinline__

constexpr int BB   = 2;
constexpr int SEQ  = 2048;
constexpr int FD   = 1024;
constexpr int NH   = 16;
constexpr int DHD  = 64;
constexpr int MROWS = BB * SEQ;

DEVI u16 f2bf(float x){
  __hip_bfloat16 h = __float2bfloat16(x);
  return __builtin_bit_cast(u16, h);
}
DEVI float bf2f(u16 u){
  return __bfloat162float(__builtin_bit_cast(__hip_bfloat16, u));
}
DEVI u32 pack2(float a, float b){
  return (u32)f2bf(a) | ((u32)f2bf(b) << 16);
}

DEVI void mfma_bf16(f32x4& acc, s16x8 a, s16x8 b){
  asm("v_mfma_f32_16x16x32_bf16 %0, %1, %2, %0" : "+v"(acc) : "v"(a), "v"(b));
}
DEVI void mfma32(f32x16& acc, s16x8 a, s16x8 b){
  asm("v_mfma_f32_32x32x16_bf16 %0, %1, %2, %0" : "+v"(acc) : "v"(a), "v"(b));
}
// v_permlane32_swap_b32 vdst, vsrc: vdst.lanes[32:63] <-> vsrc.lanes[0:31].
DEVI void plswap(u32& a, u32& b){
  asm("v_permlane32_swap_b32 %0, %1" : "+v"(a), "+v"(b));
}

#define AS1C(p) ((const __attribute__((address_space(1))) void*)(p))
#define AS3(p)  ((__attribute__((address_space(3))) void*)(p))

// ---------------------------------------------------------------------------
// Weight prep (all 4 weights, one launch): W[k][n] fp32 -> WT[n][k] bf16.
// ---------------------------------------------------------------------------
__global__ __launch_bounds__(256) void wprep_all(
    const float* __restrict__ W0, const float* __restrict__ W1,
    const float* __restrict__ W2, const float* __restrict__ W3,
    u16* __restrict__ T0, u16* __restrict__ T1,
    u16* __restrict__ T2, u16* __restrict__ T3)
{
  const int z = blockIdx.z;
  const float* W = z==0?W0 : z==1?W1 : z==2?W2 : W3;
  u16* Th       = z==0?T0 : z==1?T1 : z==2?T2 : T3;

  __shared__ float tile[64][65];
  const int kb = blockIdx.x * 64, nb = blockIdx.y * 64;
  const int t  = threadIdx.x;
  const int r  = t >> 2, c0 = (t & 3) * 16;

  const float* src = W + (size_t)(kb + r) * FD + nb + c0;
  #pragma unroll
  for (int i = 0; i < 16; i += 4){
    float4 v = *reinterpret_cast<const float4*>(src + i);
    tile[r][c0+i+0] = v.x; tile[r][c0+i+1] = v.y;
    tile[r][c0+i+2] = v.z; tile[r][c0+i+3] = v.w;
  }
  __syncthreads();

  s16x8 hA, hB;
  #pragma unroll
  for (int i = 0; i < 8; i++){
    hA[i] = (short)f2bf(tile[c0 + i][r]);
    hB[i] = (short)f2bf(tile[c0 + 8 + i][r]);
  }
  const size_t o = (size_t)(nb + r) * FD + kb + c0;
  *reinterpret_cast<s16x8*>(Th + o)     = hA;
  *reinterpret_cast<s16x8*>(Th + o + 8) = hB;
}

// ---------------------------------------------------------------------------
// Fused Q/K/V projections: one launch, blockIdx.z selects (A, W, bias, out).
// C[M,1024] = A[M,1024] @ W + bias.  128x128 tile, BK=32, 4 waves.
// z=0: Q, EPI head-split [B,H,N,DH] with oscale 1/8; z=1: K same, scale 1;
// z=2: V, transposed head-split [B,H,DH,N].
// ---------------------------------------------------------------------------
__global__ __launch_bounds__(256) void qkv_gemm(
    const float* __restrict__ qp, const float* __restrict__ kp, const float* __restrict__ vp,
    const u16* __restrict__ Wq, const u16* __restrict__ Wk, const u16* __restrict__ Wv,
    const float* __restrict__ bq, const float* __restrict__ bk, const float* __restrict__ bv,
    u16* __restrict__ Q2, u16* __restrict__ K2, u16* __restrict__ Vt2)
{
  constexpr int LDT = 40;
  __shared__ u16 sA[128][LDT];
  __shared__ u16 sW[128][LDT];

  const int z = blockIdx.z;
  const float* Ap   = z==0?qp : z==1?kp : vp;
  const u16*  Wh    = z==0?Wq : z==1?Wk : Wv;
  const float* bias = z==0?bq : z==1?bk : bv;
  u16* outp         = z==0?Q2 : z==1?K2 : Vt2;
  const float oscale = (z==0) ? 0.125f : 1.0f;
  const bool  tr     = (z==2);

  const int t    = threadIdx.x;
  const int nb0  = blockIdx.x * 128, mb0 = blockIdx.y * 128;
  const int lane = t & 63, w = t >> 6;
  const int r16  = lane & 15, g = lane >> 4;
  const int wm   = (w >> 1) * 64, wn = (w & 1) * 64;

  f32x4 acc[4][4] = {};

  for (int kb = 0; kb < FD; kb += 32){
    __syncthreads();
    #pragma unroll
    for (int s = 0; s < 2; s++){
      const int c = t + 256 * s;
      const int row = c >> 2, col = (c & 3) * 8;
      *reinterpret_cast<s16x8*>(&sW[row][col]) =
        *reinterpret_cast<const s16x8*>(Wh + (size_t)(nb0 + row) * FD + kb + col);
      const float* af = Ap + (size_t)(mb0 + row) * FD + kb + col;
      float4 v0 = *reinterpret_cast<const float4*>(af);
      float4 v1 = *reinterpret_cast<const float4*>(af + 4);
      s16x8 hv;
      hv[0]=(short)f2bf(v0.x); hv[1]=(short)f2bf(v0.y);
      hv[2]=(short)f2bf(v0.z); hv[3]=(short)f2bf(v0.w);
      hv[4]=(short)f2bf(v1.x); hv[5]=(short)f2bf(v1.y);
      hv[6]=(short)f2bf(v1.z); hv[7]=(short)f2bf(v1.w);
      *reinterpret_cast<s16x8*>(&sA[row][col]) = hv;
    }
    __syncthreads();

    s16x8 a[4], bh[4];
    #pragma unroll
    for (int i = 0; i < 4; i++){
      a[i]  = *reinterpret_cast<const s16x8*>(&sA[wm + i*16 + r16][g*8]);
      bh[i] = *reinterpret_cast<const s16x8*>(&sW[wn + i*16 + r16][g*8]);
    }
    #pragma unroll
    for (int i = 0; i < 4; i++)
      #pragma unroll
      for (int j = 0; j < 4; j++)
        mfma_bf16(acc[i][j], a[i], bh[j]);
  }

  #pragma unroll
  for (int i = 0; i < 4; i++){
    #pragma unroll
    for (int j = 0; j < 4; j++){
      const int ccol = nb0 + wn + j*16 + r16;
      const float bv = bias[ccol];
      #pragma unroll
      for (int r = 0; r < 4; r++){
        const int m = mb0 + wm + i*16 + g*4 + r;
        const float v = (acc[i][j][r] + bv) * oscale;
        const int b = m >> 11, n = m & (SEQ - 1);
        const int h = ccol >> 6, d = ccol & 63;
        const size_t idx = tr ? ((size_t)(b*NH + h)*DHD + d)*SEQ + n
                              : ((size_t)(b*NH + h)*SEQ + n)*DHD + d;
        outp[idx] = f2bf(v);
      }
    }
  }
}

// ---------------------------------------------------------------------------
// O-projection GEMM: C[M,1024] = A[M,1024] @ W + bias, A bf16, fp32 out.
// BM x 128 tile (BM=64 -> 512 blocks = 2/CU).
// ---------------------------------------------------------------------------
template<int BM>
__global__ __launch_bounds__(256) void ogemm_k(
    const u16* __restrict__ Ap, const u16* __restrict__ Wh,
    const float* __restrict__ bias, float* __restrict__ outp)
{
  constexpr int LDT = 40;
  constexpr int AI  = BM / 32;       // per-wave row frags
  __shared__ u16 sA[BM][LDT];
  __shared__ u16 sW[128][LDT];

  const int t    = threadIdx.x;
  const int nb0  = blockIdx.x * 128, mb0 = blockIdx.y * BM;
  const int lane = t & 63, w = t >> 6;
  const int r16  = lane & 15, g = lane >> 4;
  const int wm   = (w >> 1) * (BM/2), wn = (w & 1) * 64;

  f32x4 acc[AI][4] = {};

  for (int kb = 0; kb < FD; kb += 32){
    __syncthreads();
    #pragma unroll
    for (int s = 0; s < 2; s++){
      const int c = t + 256 * s;
      const int row = c >> 2, col = (c & 3) * 8;
      *reinterpret_cast<s16x8*>(&sW[row][col]) =
        *reinterpret_cast<const s16x8*>(Wh + (size_t)(nb0 + row) * FD + kb + col);
    }
    #pragma unroll
    for (int s = 0; s < BM/64; s++){
      const int c = t + 256 * s;
      const int row = c >> 2, col = (c & 3) * 8;
      *reinterpret_cast<s16x8*>(&sA[row][col]) =
        *reinterpret_cast<const s16x8*>(Ap + (size_t)(mb0 + row) * FD + kb + col);
    }
    __syncthreads();

    s16x8 a[AI], bh[4];
    #pragma unroll
    for (int i = 0; i < AI; i++)
      a[i]  = *reinterpret_cast<const s16x8*>(&sA[wm + i*16 + r16][g*8]);
    #pragma unroll
    for (int j = 0; j < 4; j++)
      bh[j] = *reinterpret_cast<const s16x8*>(&sW[wn + j*16 + r16][g*8]);
    #pragma unroll
    for (int i = 0; i < AI; i++)
      #pragma unroll
      for (int j = 0; j < 4; j++)
        mfma_bf16(acc[i][j], a[i], bh[j]);
  }

  #pragma unroll
  for (int i = 0; i < AI; i++){
    #pragma unroll
    for (int j = 0; j < 4; j++){
      const int ccol = nb0 + wn + j*16 + r16;
      const float bv = bias[ccol];
      #pragma unroll
      for (int r = 0; r < 4; r++){
        const int m = mb0 + wm + i*16 + g*4 + r;
        outp[(size_t)m * FD + ccol] = acc[i][j][r] + bv;
      }
    }
  }
}

// ---------------------------------------------------------------------------
// Flash attention, swapped-operand 32x32, 8 waves = 2 KV-groups x 4 waves.
// Group g processes KV tiles kt = 2i+g with private (m,l,O); merged via LDS.
// XCD swizzle: bh = (bid&7)*4 + ((bid>>3)&3) keeps 4 heads' KV per XCD L2.
// ---------------------------------------------------------------------------
__global__ __launch_bounds__(512, 4) void attn_k(
    const u16* __restrict__ Q2, const u16* __restrict__ K2, const u16* __restrict__ Vt2,
    u16* __restrict__ AOh)
{
  // [kv][grp][buf][64*64] = 64 KB; merge area aliases the whole block.
  __shared__ u16 smem[2][2][2][64*64];

  const int bid = blockIdx.x + 16 * blockIdx.y;
  const int qt  = bid >> 5;
  const int bh  = (bid & 7) * 4 + ((bid >> 3) & 3);

  const int t = threadIdx.x, w = t >> 6, lane = t & 63;
  const int grp = w >> 2, gw = w & 3;
  const int l31 = lane & 31, hi = lane >> 5;

  const u16* Kb = K2  + (size_t)bh * SEQ * DHD;
  const u16* Vb = Vt2 + (size_t)bh * DHD * SEQ;

  const int srow8  = lane >> 3;
  const int schunk = ((lane & 7) ^ srow8) * 8;

  const int qrow = qt*128 + gw*32 + l31;
  const u16* Qrow = Q2 + ((size_t)bh * SEQ + qrow) * DHD;
  s16x8 qf[4];
  #pragma unroll
  for (int dk = 0; dk < 4; dk++)
    qf[dk] = *reinterpret_cast<const s16x8*>(Qrow + dk*16 + hi*8);

  f32x16 ot0 = {}, ot1 = {};
  float mrun = -1e30f, lrun = 0.f;

  auto stage_tile = [&](int buf, int kt){
    #pragma unroll
    for (int i = 0; i < 2; i++){
      const int row = gw*16 + i*8 + srow8;
      const u16* kg = Kb + (size_t)(kt*64 + row) * DHD + schunk;
      const u16* vg = Vb + (size_t)row * SEQ + kt*64 + schunk;
      __builtin_amdgcn_global_load_lds(AS1C(kg), AS3(&smem[0][grp][buf][(gw*16 + i*8)*64]), 16, 0, 0);
      __builtin_amdgcn_global_load_lds(AS1C(vg), AS3(&smem[1][grp][buf][(gw*16 + i*8)*64]), 16, 0, 0);
    }
  };
  auto lds16 = [](const u16* base, int row, int colbyte) -> s16x8 {
    int off = (row << 7) + colbyte;
    off ^= (row & 7) << 4;
    return *reinterpret_cast<const s16x8*>(reinterpret_cast<const char*>(base) + off);
  };

  constexpr int NIT = SEQ / 64 / 2;   // 16 tiles per group
  stage_tile(0, grp);
  __syncthreads();

  for (int i = 0; i < NIT; i++){
    const int buf = i & 1;
    if (i + 1 < NIT) stage_tile(buf ^ 1, 2*(i+1) + grp);
    const u16* sK = &smem[0][grp][buf][0];
    const u16* sV = &smem[1][grp][buf][0];

    // ---- S^T = K · Q^T ----
    f32x16 st0 = {}, st1 = {};
    __builtin_amdgcn_s_setprio(1);
    #pragma unroll
    for (int dk = 0; dk < 4; dk++){
      s16x8 kf0 = lds16(sK, l31,      dk*32 + hi*16);
      s16x8 kf1 = lds16(sK, 32 + l31, dk*32 + hi*16);
      mfma32(st0, kf0, qf[dk]);
      mfma32(st1, kf1, qf[dk]);
    }
    __builtin_amdgcn_s_setprio(0);

    // ---- online softmax, scalar state per lane (q = lane&31) ----
    float mx[8];
    #pragma unroll
    for (int r = 0; r < 8; r++)
      mx[r] = fmaxf(fmaxf(st0[r], st0[r+8]), fmaxf(st1[r], st1[r+8]));
    float pmax = fmaxf(fmaxf(fmaxf(mx[0],mx[1]), fmaxf(mx[2],mx[3])),
                       fmaxf(fmaxf(mx[4],mx[5]), fmaxf(mx[6],mx[7])));
    pmax = fmaxf(pmax, __shfl_xor(pmax, 32, 64));

    if (!__all(pmax <= mrun + 8.f)){      // defer-max (T13)
      float mnew = fmaxf(mrun, pmax);
      float alp = __expf(mrun - mnew);
      mrun = mnew;
      lrun *= alp;
      #pragma unroll
      for (int r = 0; r < 16; r++){ ot0[r] *= alp; ot1[r] *= alp; }
    }

    #pragma unroll
    for (int r = 0; r < 16; r++){
      st0[r] = __expf(st0[r] - mrun);
      st1[r] = __expf(st1[r] - mrun);
    }
    float s8[8];
    #pragma unroll
    for (int r = 0; r < 8; r++)
      s8[r] = (st0[r] + st0[r+8]) + (st1[r] + st1[r+8]);
    float psum = ((s8[0]+s8[1])+(s8[2]+s8[3])) + ((s8[4]+s8[5])+(s8[6]+s8[7]));
    psum += __shfl_xor(psum, 32, 64);
    lrun += psum;

    // ---- P^T -> B-fragments via pack + permlane32_swap ----
    u32 pw[16];
    #pragma unroll
    for (int g2 = 0; g2 < 4; g2++){
      pw[g2*2+0]   = pack2(st0[g2*4+0], st0[g2*4+1]);
      pw[g2*2+1]   = pack2(st0[g2*4+2], st0[g2*4+3]);
      pw[8+g2*2+0] = pack2(st1[g2*4+0], st1[g2*4+1]);
      pw[8+g2*2+1] = pack2(st1[g2*4+2], st1[g2*4+3]);
    }
    s16x8 pb[4];
    #pragma unroll
    for (int ks = 0; ks < 4; ks++){
      const int e = (ks>>1)*8 + (ks&1)*4;
      u32 w0 = pw[e+0], w1 = pw[e+1], w2 = pw[e+2], w3 = pw[e+3];
      plswap(w0, w2);
      plswap(w1, w3);
      u32x4 wv = { w0, w1, w2, w3 };
      pb[ks] = __builtin_bit_cast(s16x8, wv);
    }

    // ---- O^T += V^T · P^T ----
    __builtin_amdgcn_s_setprio(1);
    #pragma unroll
    for (int ks = 0; ks < 4; ks++){
      s16x8 vf0 = lds16(sV, l31,      ks*32 + hi*16);
      s16x8 vf1 = lds16(sV, 32 + l31, ks*32 + hi*16);
      mfma32(ot0, vf0, pb[ks]);
      mfma32(ot1, vf1, pb[ks]);
    }
    __builtin_amdgcn_s_setprio(0);

    __syncthreads();   // drains stage loads + guards buffer reuse
  }

  // ---- merge the two KV-groups via LDS (stride-68 fp32 to spread banks) ----
  float* sO = reinterpret_cast<float*>(&smem[0][0][0][0]);   // 128 x 68 fp32
  float* sM = reinterpret_cast<float*>(&smem[0][0][0][0]) + 128*68; // 128 x 2
  const int ql = gw*32 + l31;

  if (grp == 1){
    #pragma unroll
    for (int r4 = 0; r4 < 4; r4++){
      const int d0 = r4*8 + hi*4;
      #pragma unroll
      for (int j = 0; j < 4; j++){
        sO[ql*68 + d0 + j]      = ot0[r4*4+j];
        sO[ql*68 + 32 + d0 + j] = ot1[r4*4+j];
      }
    }
    if (hi == 0){ sM[ql*2+0] = mrun; sM[ql*2+1] = lrun; }
  }
  __syncthreads();
  if (grp == 0){
    const float m1 = sM[ql*2+0], l1 = sM[ql*2+1];
    const float M  = fmaxf(mrun, m1);
    const float w0 = __expf(mrun - M), w1e = __expf(m1 - M);
    const float inv = 1.0f / (lrun*w0 + l1*w1e);

    const int b = bh >> 4, h = bh & 15;
    u16* orow = AOh + ((size_t)b*SEQ + qrow) * FD + h*64;
    #pragma unroll
    for (int r4 = 0; r4 < 4; r4++){
      const int d0 = r4*8 + hi*4;
      u16x4 v0, v1;
      #pragma unroll
      for (int j = 0; j < 4; j++){
        v0[j] = f2bf((ot0[r4*4+j]*w0 + sO[ql*68 + d0 + j]*w1e) * inv);
        v1[j] = f2bf((ot1[r4*4+j]*w0 + sO[ql*68 + 32 + d0 + j]*w1e) * inv);
      }
      *reinterpret_cast<u16x4*>(orow + d0)      = v0;
      *reinterpret_cast<u16x4*>(orow + 32 + d0) = v1;
    }
  }
}

// ---------------------------------------------------------------------------
extern "C" void kernel_launch(void* const* d_in, const int* in_sizes, int n_in,
                              void* d_out, int out_size, void* d_ws, size_t ws_size,
                              hipStream_t stream)
{
  const float* q  = (const float*)d_in[0];
  const float* k  = (const float*)d_in[1];
  const float* v  = (const float*)d_in[2];
  const float* Wq = (const float*)d_in[3];
  const float* bq = (const float*)d_in[4];
  const float* Wk = (const float*)d_in[5];
  const float* bk = (const float*)d_in[6];
  const float* Wv = (const float*)d_in[7];
  const float* bv = (const float*)d_in[8];
  const float* Wo = (const float*)d_in[9];
  const float* bo = (const float*)d_in[10];
  float* out = (float*)d_out;
  (void)in_sizes; (void)n_in; (void)out_size; (void)ws_size;

  char* ws = (char*)d_ws;
  size_t off = 0;
  auto alloc = [&](size_t bytes) -> char* {
    char* p = ws + off;
    off += (bytes + 255) & ~(size_t)255;
    return p;
  };
  const size_t WB = (size_t)FD * FD * sizeof(u16);             // 2 MB
  u16* WqTh = (u16*)alloc(WB);
  u16* WkTh = (u16*)alloc(WB);
  u16* WvTh = (u16*)alloc(WB);
  u16* WoTh = (u16*)alloc(WB);
  const size_t QB = (size_t)BB * NH * SEQ * DHD * sizeof(u16); // 8 MB
  u16* Q2  = (u16*)alloc(QB);
  u16* K2  = (u16*)alloc(QB);
  u16* Vt2 = (u16*)alloc(QB);
  const size_t AB = (size_t)BB * SEQ * FD * sizeof(u16);       // 8 MB
  u16* AOh = (u16*)alloc(AB);

  wprep_all<<<dim3(16,16,4), 256, 0, stream>>>(Wq, Wk, Wv, Wo, WqTh, WkTh, WvTh, WoTh);

  qkv_gemm<<<dim3(8,32,3), 256, 0, stream>>>(q, k, v, WqTh, WkTh, WvTh,
                                             bq, bk, bv, Q2, K2, Vt2);

  attn_k<<<dim3(16,32), 512, 0, stream>>>(Q2, K2, Vt2, AOh);

  ogemm_k<64><<<dim3(8,64), 256, 0, stream>>>(AOh, WoTh, bo, out);
}

// Round 5
// 138.500 us; speedup vs baseline: 1.9906x; 1.1110x over previous
//
#include <hip/hip_runtime.h>
#include <hip/hip_bf16.h>

typedef float f32x4  __attribute__((ext_vector_type(4)));
typedef float f32x16 __attribute__((ext_vector_type(16)));
typedef short s16x8  __attribute__((ext_vector_type(8)));
typedef unsigned int u32;
typedef unsigned short u16;
typedef u16 u16x4 __attribute__((ext_vector_type(4)));
typedef u32 u32x4 __attribute__((ext_vector_type(4)));

#define DEVI static __device__ __forceinline__

constexpr int BB   = 2;
constexpr int SEQ  = 2048;
constexpr int FD   = 1024;
constexpr int NH   = 16;
constexpr int DHD  = 64;

DEVI u16 f2bf(float x){
  __hip_bfloat16 h = __float2bfloat16(x);
  return __builtin_bit_cast(u16, h);
}
DEVI float bf2f(u16 u){
  return __bfloat162float(__builtin_bit_cast(__hip_bfloat16, u));
}
DEVI u32 pack2(float a, float b){
  return (u32)f2bf(a) | ((u32)f2bf(b) << 16);
}

DEVI void mfma_bf16(f32x4& acc, s16x8 a, s16x8 b){
  asm("v_mfma_f32_16x16x32_bf16 %0, %1, %2, %0" : "+v"(acc) : "v"(a), "v"(b));
}
DEVI void mfma32(f32x16& acc, s16x8 a, s16x8 b){
  asm("v_mfma_f32_32x32x16_bf16 %0, %1, %2, %0" : "+v"(acc) : "v"(a), "v"(b));
}
// v_permlane32_swap_b32 vdst, vsrc: vdst.lanes[32:63] <-> vsrc.lanes[0:31].
DEVI void plswap(u32& a, u32& b){
  asm("v_permlane32_swap_b32 %0, %1" : "+v"(a), "+v"(b));
}

#define AS1C(p) ((const __attribute__((address_space(1))) void*)(p))
#define AS3(p)  ((__attribute__((address_space(3))) void*)(p))

// ---------------------------------------------------------------------------
// Weight prep (all 4 weights, one launch): W[k][n] fp32 -> WT[n][k] bf16.
// ---------------------------------------------------------------------------
__global__ __launch_bounds__(256) void wprep_all(
    const float* __restrict__ W0, const float* __restrict__ W1,
    const float* __restrict__ W2, const float* __restrict__ W3,
    u16* __restrict__ T0, u16* __restrict__ T1,
    u16* __restrict__ T2, u16* __restrict__ T3)
{
  const int z = blockIdx.z;
  const float* W = z==0?W0 : z==1?W1 : z==2?W2 : W3;
  u16* Th       = z==0?T0 : z==1?T1 : z==2?T2 : T3;

  __shared__ float tile[64][65];
  const int kb = blockIdx.x * 64, nb = blockIdx.y * 64;
  const int t  = threadIdx.x;
  const int r  = t >> 2, c0 = (t & 3) * 16;

  const float* src = W + (size_t)(kb + r) * FD + nb + c0;
  #pragma unroll
  for (int i = 0; i < 16; i += 4){
    float4 v = *reinterpret_cast<const float4*>(src + i);
    tile[r][c0+i+0] = v.x; tile[r][c0+i+1] = v.y;
    tile[r][c0+i+2] = v.z; tile[r][c0+i+3] = v.w;
  }
  __syncthreads();

  s16x8 hA, hB;
  #pragma unroll
  for (int i = 0; i < 8; i++){
    hA[i] = (short)f2bf(tile[c0 + i][r]);
    hB[i] = (short)f2bf(tile[c0 + 8 + i][r]);
  }
  const size_t o = (size_t)(nb + r) * FD + kb + c0;
  *reinterpret_cast<s16x8*>(Th + o)     = hA;
  *reinterpret_cast<s16x8*>(Th + o + 8) = hB;
}

// ---------------------------------------------------------------------------
// Fused Q/K/V projections, gl_lds 2-phase template.
// C[4096,1024] = A @ W + bias; A fp32 staged raw into LDS (XOR-swizzled,
// pre-swizzled source), converted to bf16 at fragment read (same f2bf as
// before -> bit-identical results). W bf16 gl_lds. Double-buffered, one
// barrier per BK=32 step. XCD-chunked block swizzle: all 8 N-blocks of an
// M-strip on one XCD -> A-panel fetched into exactly one L2.
// ---------------------------------------------------------------------------
__global__ __launch_bounds__(256, 3) void qkv_gemm(
    const float* __restrict__ qp, const float* __restrict__ kp, const float* __restrict__ vp,
    const u16* __restrict__ Wq, const u16* __restrict__ Wk, const u16* __restrict__ Wv,
    const float* __restrict__ bq, const float* __restrict__ bk, const float* __restrict__ bv,
    u16* __restrict__ Q2, u16* __restrict__ K2, u16* __restrict__ Vt2)
{
  __shared__ float sA[2][128*32];   // fp32 tile, rows of 128B, swizzled
  __shared__ u16   sW[2][128*32];   // bf16 tile, rows of 64B, swizzled

  // XCD swizzle: 768 blocks = 96 strips x 8 nb; strips chunked per XCD.
  const int bid  = blockIdx.x;
  const int xcd  = bid & 7, idx = bid >> 3;          // idx 0..95
  const int strip = xcd * 12 + (idx >> 3);           // 0..95
  const int nb   = idx & 7;
  const int z    = strip >> 5, my = strip & 31;

  const float* Ap   = z==0?qp : z==1?kp : vp;
  const u16*  Wh    = z==0?Wq : z==1?Wk : Wv;
  const float* bias = z==0?bq : z==1?bk : bv;
  u16* outp         = z==0?Q2 : z==1?K2 : Vt2;
  const float oscale = (z==0) ? 0.125f : 1.0f;
  const bool  tr     = (z==2);

  const int t    = threadIdx.x;
  const int nb0  = nb * 128, mb0 = my * 128;
  const int lane = t & 63, w = t >> 6;
  const int r16  = lane & 15, g = lane >> 4;
  const int wm   = (w >> 1) * 64, wn = (w & 1) * 64;

  // staging lane->source swizzle (rule #21: linear LDS dest, pre-swz src)
  const int aRow = lane >> 3, aChunk = (lane & 7) ^ aRow;        // fp32 tile: 8 chunks/row
  const int wRow = lane >> 2, wChunk = (lane & 3) ^ (wRow & 3);  // bf16 tile: 4 chunks/row

  auto stage = [&](int buf, int kb){
    #pragma unroll
    for (int i = 0; i < 4; i++){     // A: 4 issues x 32 rows
      const int row = i*32 + w*8 + aRow;
      const float* ag = Ap + (size_t)(mb0 + row) * FD + kb + aChunk*4;
      __builtin_amdgcn_global_load_lds(AS1C(ag), AS3(&sA[buf][(i*32 + w*8)*32]), 16, 0, 0);
    }
    #pragma unroll
    for (int i = 0; i < 2; i++){     // W: 2 issues x 64 rows
      const int row = i*64 + w*16 + wRow;
      const u16* wg = Wh + (size_t)(nb0 + row) * FD + kb + wChunk*8;
      __builtin_amdgcn_global_load_lds(AS1C(wg), AS3(&sW[buf][(i*64 + w*16)*32]), 16, 0, 0);
    }
  };
  auto ldsA = [&](const float* base, int row, int gg) -> s16x8 {
    const char* p = reinterpret_cast<const char*>(base);
    const int roff = row << 7, sw = (row & 7) << 4;
    f32x4 lo = *reinterpret_cast<const f32x4*>(p + (roff + ((gg*32)      ^ sw)));
    f32x4 hi = *reinterpret_cast<const f32x4*>(p + (roff + ((gg*32 + 16) ^ sw)));
    s16x8 r;
    #pragma unroll
    for (int j = 0; j < 4; j++){
      r[j]   = (short)f2bf(lo[j]);
      r[4+j] = (short)f2bf(hi[j]);
    }
    return r;
  };
  auto ldsW = [&](const u16* base, int row, int gg) -> s16x8 {
    const char* p = reinterpret_cast<const char*>(base);
    const int off = (row << 6) + ((gg*16) ^ ((row & 3) << 4));
    return *reinterpret_cast<const s16x8*>(p + off);
  };

  f32x4 acc[4][4] = {};

  stage(0, 0);
  __syncthreads();

  for (int it = 0; it < FD/32; it++){
    const int buf = it & 1;
    if (it + 1 < FD/32) stage(buf ^ 1, (it + 1) * 32);

    s16x8 a[4], bh[4];
    #pragma unroll
    for (int i = 0; i < 4; i++)
      a[i]  = ldsA(sA[buf], wm + i*16 + r16, g);
    #pragma unroll
    for (int j = 0; j < 4; j++)
      bh[j] = ldsW(sW[buf], wn + j*16 + r16, g);

    __builtin_amdgcn_s_setprio(1);
    #pragma unroll
    for (int i = 0; i < 4; i++)
      #pragma unroll
      for (int j = 0; j < 4; j++)
        mfma_bf16(acc[i][j], a[i], bh[j]);
    __builtin_amdgcn_s_setprio(0);

    __syncthreads();
  }

  #pragma unroll
  for (int i = 0; i < 4; i++){
    #pragma unroll
    for (int j = 0; j < 4; j++){
      const int ccol = nb0 + wn + j*16 + r16;
      const float bv = bias[ccol];
      #pragma unroll
      for (int r = 0; r < 4; r++){
        const int m = mb0 + wm + i*16 + g*4 + r;
        const float v = (acc[i][j][r] + bv) * oscale;
        const int b = m >> 11, n = m & (SEQ - 1);
        const int h = ccol >> 6, d = ccol & 63;
        const size_t o = tr ? ((size_t)(b*NH + h)*DHD + d)*SEQ + n
                            : ((size_t)(b*NH + h)*SEQ + n)*DHD + d;
        outp[o] = f2bf(v);
      }
    }
  }
}

// ---------------------------------------------------------------------------
// O-projection GEMM, same template, A bf16.  64x128 tile, 512 blocks.
// ---------------------------------------------------------------------------
__global__ __launch_bounds__(256, 3) void ogemm_k(
    const u16* __restrict__ Ap, const u16* __restrict__ Wh,
    const float* __restrict__ bias, float* __restrict__ outp)
{
  __shared__ u16 sA[2][64*32];
  __shared__ u16 sW[2][128*32];

  const int bid  = blockIdx.x;
  const int xcd  = bid & 7, idx = bid >> 3;          // idx 0..63
  const int my   = xcd * 8 + (idx >> 3);             // 0..63
  const int nb   = idx & 7;

  const int t    = threadIdx.x;
  const int nb0  = nb * 128, mb0 = my * 64;
  const int lane = t & 63, w = t >> 6;
  const int r16  = lane & 15, g = lane >> 4;
  const int wm   = (w >> 1) * 32, wn = (w & 1) * 64;

  const int wRow = lane >> 2, wChunk = (lane & 3) ^ (wRow & 3);

  auto stage = [&](int buf, int kb){
    {   // A: 1 issue x 64 rows
      const int row = w*16 + wRow;
      const u16* ag = Ap + (size_t)(mb0 + row) * FD + kb + wChunk*8;
      __builtin_amdgcn_global_load_lds(AS1C(ag), AS3(&sA[buf][(w*16)*32]), 16, 0, 0);
    }
    #pragma unroll
    for (int i = 0; i < 2; i++){   // W: 2 issues x 64 rows
      const int row = i*64 + w*16 + wRow;
      const u16* wg = Wh + (size_t)(nb0 + row) * FD + kb + wChunk*8;
      __builtin_amdgcn_global_load_lds(AS1C(wg), AS3(&sW[buf][(i*64 + w*16)*32]), 16, 0, 0);
    }
  };
  auto ldsW = [&](const u16* base, int row, int gg) -> s16x8 {
    const char* p = reinterpret_cast<const char*>(base);
    const int off = (row << 6) + ((gg*16) ^ ((row & 3) << 4));
    return *reinterpret_cast<const s16x8*>(p + off);
  };

  f32x4 acc[2][4] = {};

  stage(0, 0);
  __syncthreads();

  for (int it = 0; it < FD/32; it++){
    const int buf = it & 1;
    if (it + 1 < FD/32) stage(buf ^ 1, (it + 1) * 32);

    s16x8 a[2], bh[4];
    #pragma unroll
    for (int i = 0; i < 2; i++)
      a[i]  = ldsW(sA[buf], wm + i*16 + r16, g);
    #pragma unroll
    for (int j = 0; j < 4; j++)
      bh[j] = ldsW(sW[buf], wn + j*16 + r16, g);

    __builtin_amdgcn_s_setprio(1);
    #pragma unroll
    for (int i = 0; i < 2; i++)
      #pragma unroll
      for (int j = 0; j < 4; j++)
        mfma_bf16(acc[i][j], a[i], bh[j]);
    __builtin_amdgcn_s_setprio(0);

    __syncthreads();
  }

  #pragma unroll
  for (int i = 0; i < 2; i++){
    #pragma unroll
    for (int j = 0; j < 4; j++){
      const int ccol = nb0 + wn + j*16 + r16;
      const float bv = bias[ccol];
      #pragma unroll
      for (int r = 0; r < 4; r++){
        const int m = mb0 + wm + i*16 + g*4 + r;
        outp[(size_t)m * FD + ccol] = acc[i][j][r] + bv;
      }
    }
  }
}

// ---------------------------------------------------------------------------
// Flash attention (unchanged from R4): swapped-operand 32x32, 8 waves =
// 2 KV-groups x 4; group-private (m,l,O) merged via LDS at the end.
// ---------------------------------------------------------------------------
__global__ __launch_bounds__(512, 4) void attn_k(
    const u16* __restrict__ Q2, const u16* __restrict__ K2, const u16* __restrict__ Vt2,
    u16* __restrict__ AOh)
{
  __shared__ u16 smem[2][2][2][64*64];

  const int bid = blockIdx.x + 16 * blockIdx.y;
  const int qt  = bid >> 5;
  const int bh  = (bid & 7) * 4 + ((bid >> 3) & 3);

  const int t = threadIdx.x, w = t >> 6, lane = t & 63;
  const int grp = w >> 2, gw = w & 3;
  const int l31 = lane & 31, hi = lane >> 5;

  const u16* Kb = K2  + (size_t)bh * SEQ * DHD;
  const u16* Vb = Vt2 + (size_t)bh * DHD * SEQ;

  const int srow8  = lane >> 3;
  const int schunk = ((lane & 7) ^ srow8) * 8;

  const int qrow = qt*128 + gw*32 + l31;
  const u16* Qrow = Q2 + ((size_t)bh * SEQ + qrow) * DHD;
  s16x8 qf[4];
  #pragma unroll
  for (int dk = 0; dk < 4; dk++)
    qf[dk] = *reinterpret_cast<const s16x8*>(Qrow + dk*16 + hi*8);

  f32x16 ot0 = {}, ot1 = {};
  float mrun = -1e30f, lrun = 0.f;

  auto stage_tile = [&](int buf, int kt){
    #pragma unroll
    for (int i = 0; i < 2; i++){
      const int row = gw*16 + i*8 + srow8;
      const u16* kg = Kb + (size_t)(kt*64 + row) * DHD + schunk;
      const u16* vg = Vb + (size_t)row * SEQ + kt*64 + schunk;
      __builtin_amdgcn_global_load_lds(AS1C(kg), AS3(&smem[0][grp][buf][(gw*16 + i*8)*64]), 16, 0, 0);
      __builtin_amdgcn_global_load_lds(AS1C(vg), AS3(&smem[1][grp][buf][(gw*16 + i*8)*64]), 16, 0, 0);
    }
  };
  auto lds16 = [](const u16* base, int row, int colbyte) -> s16x8 {
    int off = (row << 7) + colbyte;
    off ^= (row & 7) << 4;
    return *reinterpret_cast<const s16x8*>(reinterpret_cast<const char*>(base) + off);
  };

  constexpr int NIT = SEQ / 64 / 2;
  stage_tile(0, grp);
  __syncthreads();

  for (int i = 0; i < NIT; i++){
    const int buf = i & 1;
    if (i + 1 < NIT) stage_tile(buf ^ 1, 2*(i+1) + grp);
    const u16* sK = &smem[0][grp][buf][0];
    const u16* sV = &smem[1][grp][buf][0];

    f32x16 st0 = {}, st1 = {};
    __builtin_amdgcn_s_setprio(1);
    #pragma unroll
    for (int dk = 0; dk < 4; dk++){
      s16x8 kf0 = lds16(sK, l31,      dk*32 + hi*16);
      s16x8 kf1 = lds16(sK, 32 + l31, dk*32 + hi*16);
      mfma32(st0, kf0, qf[dk]);
      mfma32(st1, kf1, qf[dk]);
    }
    __builtin_amdgcn_s_setprio(0);

    float mx[8];
    #pragma unroll
    for (int r = 0; r < 8; r++)
      mx[r] = fmaxf(fmaxf(st0[r], st0[r+8]), fmaxf(st1[r], st1[r+8]));
    float pmax = fmaxf(fmaxf(fmaxf(mx[0],mx[1]), fmaxf(mx[2],mx[3])),
                       fmaxf(fmaxf(mx[4],mx[5]), fmaxf(mx[6],mx[7])));
    pmax = fmaxf(pmax, __shfl_xor(pmax, 32, 64));

    if (!__all(pmax <= mrun + 8.f)){
      float mnew = fmaxf(mrun, pmax);
      float alp = __expf(mrun - mnew);
      mrun = mnew;
      lrun *= alp;
      #pragma unroll
      for (int r = 0; r < 16; r++){ ot0[r] *= alp; ot1[r] *= alp; }
    }

    #pragma unroll
    for (int r = 0; r < 16; r++){
      st0[r] = __expf(st0[r] - mrun);
      st1[r] = __expf(st1[r] - mrun);
    }
    float s8[8];
    #pragma unroll
    for (int r = 0; r < 8; r++)
      s8[r] = (st0[r] + st0[r+8]) + (st1[r] + st1[r+8]);
    float psum = ((s8[0]+s8[1])+(s8[2]+s8[3])) + ((s8[4]+s8[5])+(s8[6]+s8[7]));
    psum += __shfl_xor(psum, 32, 64);
    lrun += psum;

    u32 pw[16];
    #pragma unroll
    for (int g2 = 0; g2 < 4; g2++){
      pw[g2*2+0]   = pack2(st0[g2*4+0], st0[g2*4+1]);
      pw[g2*2+1]   = pack2(st0[g2*4+2], st0[g2*4+3]);
      pw[8+g2*2+0] = pack2(st1[g2*4+0], st1[g2*4+1]);
      pw[8+g2*2+1] = pack2(st1[g2*4+2], st1[g2*4+3]);
    }
    s16x8 pb[4];
    #pragma unroll
    for (int ks = 0; ks < 4; ks++){
      const int e = (ks>>1)*8 + (ks&1)*4;
      u32 w0 = pw[e+0], w1 = pw[e+1], w2 = pw[e+2], w3 = pw[e+3];
      plswap(w0, w2);
      plswap(w1, w3);
      u32x4 wv = { w0, w1, w2, w3 };
      pb[ks] = __builtin_bit_cast(s16x8, wv);
    }

    __builtin_amdgcn_s_setprio(1);
    #pragma unroll
    for (int ks = 0; ks < 4; ks++){
      s16x8 vf0 = lds16(sV, l31,      ks*32 + hi*16);
      s16x8 vf1 = lds16(sV, 32 + l31, ks*32 + hi*16);
      mfma32(ot0, vf0, pb[ks]);
      mfma32(ot1, vf1, pb[ks]);
    }
    __builtin_amdgcn_s_setprio(0);

    __syncthreads();
  }

  float* sO = reinterpret_cast<float*>(&smem[0][0][0][0]);
  float* sM = reinterpret_cast<float*>(&smem[0][0][0][0]) + 128*68;
  const int ql = gw*32 + l31;

  if (grp == 1){
    #pragma unroll
    for (int r4 = 0; r4 < 4; r4++){
      const int d0 = r4*8 + hi*4;
      #pragma unroll
      for (int j = 0; j < 4; j++){
        sO[ql*68 + d0 + j]      = ot0[r4*4+j];
        sO[ql*68 + 32 + d0 + j] = ot1[r4*4+j];
      }
    }
    if (hi == 0){ sM[ql*2+0] = mrun; sM[ql*2+1] = lrun; }
  }
  __syncthreads();
  if (grp == 0){
    const float m1 = sM[ql*2+0], l1 = sM[ql*2+1];
    const float M  = fmaxf(mrun, m1);
    const float w0 = __expf(mrun - M), w1e = __expf(m1 - M);
    const float inv = 1.0f / (lrun*w0 + l1*w1e);

    const int b = bh >> 4, h = bh & 15;
    u16* orow = AOh + ((size_t)b*SEQ + qrow) * FD + h*64;
    #pragma unroll
    for (int r4 = 0; r4 < 4; r4++){
      const int d0 = r4*8 + hi*4;
      u16x4 v0, v1;
      #pragma unroll
      for (int j = 0; j < 4; j++){
        v0[j] = f2bf((ot0[r4*4+j]*w0 + sO[ql*68 + d0 + j]*w1e) * inv);
        v1[j] = f2bf((ot1[r4*4+j]*w0 + sO[ql*68 + 32 + d0 + j]*w1e) * inv);
      }
      *reinterpret_cast<u16x4*>(orow + d0)      = v0;
      *reinterpret_cast<u16x4*>(orow + 32 + d0) = v1;
    }
  }
}

// ---------------------------------------------------------------------------
extern "C" void kernel_launch(void* const* d_in, const int* in_sizes, int n_in,
                              void* d_out, int out_size, void* d_ws, size_t ws_size,
                              hipStream_t stream)
{
  const float* q  = (const float*)d_in[0];
  const float* k  = (const float*)d_in[1];
  const float* v  = (const float*)d_in[2];
  const float* Wq = (const float*)d_in[3];
  const float* bq = (const float*)d_in[4];
  const float* Wk = (const float*)d_in[5];
  const float* bk = (const float*)d_in[6];
  const float* Wv = (const float*)d_in[7];
  const float* bv = (const float*)d_in[8];
  const float* Wo = (const float*)d_in[9];
  const float* bo = (const float*)d_in[10];
  float* out = (float*)d_out;
  (void)in_sizes; (void)n_in; (void)out_size; (void)ws_size;

  char* ws = (char*)d_ws;
  size_t off = 0;
  auto alloc = [&](size_t bytes) -> char* {
    char* p = ws + off;
    off += (bytes + 255) & ~(size_t)255;
    return p;
  };
  const size_t WB = (size_t)FD * FD * sizeof(u16);             // 2 MB
  u16* WqTh = (u16*)alloc(WB);
  u16* WkTh = (u16*)alloc(WB);
  u16* WvTh = (u16*)alloc(WB);
  u16* WoTh = (u16*)alloc(WB);
  const size_t QB = (size_t)BB * NH * SEQ * DHD * sizeof(u16); // 8 MB
  u16* Q2  = (u16*)alloc(QB);
  u16* K2  = (u16*)alloc(QB);
  u16* Vt2 = (u16*)alloc(QB);
  const size_t AB = (size_t)BB * SEQ * FD * sizeof(u16);       // 8 MB
  u16* AOh = (u16*)alloc(AB);

  wprep_all<<<dim3(16,16,4), 256, 0, stream>>>(Wq, Wk, Wv, Wo, WqTh, WkTh, WvTh, WoTh);

  qkv_gemm<<<dim3(768), 256, 0, stream>>>(q, k, v, WqTh, WkTh, WvTh,
                                          bq, bk, bv, Q2, K2, Vt2);

  attn_k<<<dim3(16,32), 512, 0, stream>>>(Q2, K2, Vt2, AOh);

  ogemm_k<<<dim3(512), 256, 0, stream>>>(AOh, WoTh, bo, out);
}